// Round 1
// baseline (56383.148 us; speedup 1.0000x reference)
//
#include <hip/hip_runtime.h>

typedef __attribute__((ext_vector_type(8))) __bf16 bf16x8;
typedef __attribute__((ext_vector_type(4))) float f32x4;
typedef __attribute__((ext_vector_type(4))) unsigned int u32x4;

constexpr int NB = 4096, NT = 64, NZ = 128, NK = 256, NH = 512, NY = 128;
constexpr int NGATE = 2048;   // 4*H
constexpr int KA = 768;       // A K-dim: [h(512) | key_r(0..255)]; key_r[256] via rank-1
constexpr int LDA = 776;      // LDS row stride for A (ushorts), padded

__device__ __forceinline__ unsigned short f2bf(float f) {
    unsigned int u = __float_as_uint(f);
    return (unsigned short)((u + 0x7fffu + ((u >> 16) & 1u)) >> 16);  // RNE
}
__device__ __forceinline__ float bf2f(unsigned short h) {
    return __uint_as_float(((unsigned int)h) << 16);
}
__device__ __forceinline__ float sigm(float x) { return 1.f / (1.f + __expf(-x)); }
__device__ __forceinline__ float tanh_f(float x) {
    float e = __expf(-2.f * x);
    return (1.f - e) / (1.f + e);
}
__device__ __forceinline__ f32x4 mfma16(u32x4 a, u32x4 b, f32x4 c) {
    return __builtin_amdgcn_mfma_f32_16x16x32_bf16(
        __builtin_bit_cast(bf16x8, a), __builtin_bit_cast(bf16x8, b), c, 0, 0, 0);
}

// ---------------------------------------------------------------------------
// Prep: split W=[W_h;W_i[0:256]] (768x2048) and W_kw (512x256) into bf16 hi/lo,
// swizzled to MFMA B-fragment order: elem off = ((k>>3)*N + n)*8 + (k&7)
// so lane l at k-block kb loads 16B at ((kb*4 + (l>>4))*N + n)*8.
// ---------------------------------------------------------------------------
__launch_bounds__(256)
__global__ void prep_w(const float* __restrict__ Wi, const float* __restrict__ Wh,
                       const float* __restrict__ Wkw,
                       unsigned short* __restrict__ WBhi, unsigned short* __restrict__ WBlo,
                       unsigned short* __restrict__ KBhi, unsigned short* __restrict__ KBlo) {
    int id = blockIdx.x * 256 + threadIdx.x;
    int kg, n, N;
    unsigned short *dh, *dl;
    bool gates;
    if (id < 96 * 2048) {
        kg = id >> 11; n = id & 2047; N = 2048; dh = WBhi; dl = WBlo; gates = true;
    } else {
        int id2 = id - 96 * 2048;
        if (id2 >= 64 * 256) return;
        kg = id2 >> 8; n = id2 & 255; N = 256; dh = KBhi; dl = KBlo; gates = false;
    }
    unsigned int hu[4], lu[4];
#pragma unroll
    for (int j2 = 0; j2 < 4; ++j2) {
        unsigned int hh2[2], ll2[2];
#pragma unroll
        for (int s = 0; s < 2; ++s) {
            int k = kg * 8 + j2 * 2 + s;
            float v;
            if (gates) v = (k < 512) ? Wh[(size_t)k * 2048 + n] : Wi[(size_t)(k - 512) * 2048 + n];
            else       v = Wkw[(size_t)k * 256 + n];
            unsigned short h = f2bf(v);
            hh2[s] = h;
            ll2[s] = f2bf(v - bf2f(h));
        }
        hu[j2] = hh2[0] | (hh2[1] << 16);
        lu[j2] = ll2[0] | (ll2[1] << 16);
    }
    size_t off = ((size_t)kg * N + n) * 8;
    u32x4 hv = {hu[0], hu[1], hu[2], hu[3]};
    u32x4 lv = {lu[0], lu[1], lu[2], lu[3]};
    *(u32x4*)(dh + off) = hv;
    *(u32x4*)(dl + off) = lv;
}

// ---------------------------------------------------------------------------
// Gram: G[b][i][j] = z[b,i] . z[b,j]  (64x64 per row) via bf16x3 MFMA
// ---------------------------------------------------------------------------
__launch_bounds__(256)
__global__ void gram_k(const float* __restrict__ z, float* __restrict__ G) {
    __shared__ unsigned short Zhi[64][136];
    __shared__ unsigned short Zlo[64][136];
    const int b = blockIdx.x;
    const int tid = threadIdx.x;
    const float* zb = z + (size_t)b * (NT * NZ);
    for (int idx = tid; idx < NT * NZ; idx += 256) {
        float v = zb[idx];
        int tt = idx >> 7, kk = idx & 127;
        unsigned short h = f2bf(v);
        Zhi[tt][kk] = h;
        Zlo[tt][kk] = f2bf(v - bf2f(h));
    }
    __syncthreads();
    const int w = tid >> 6, l = tid & 63;
    const int l15 = l & 15, lg = l >> 4;
    const int ti0 = w * 16;
    float* Gb = G + (size_t)b * 4096;
    for (int u = 0; u < 4; ++u) {
        int tj0 = u * 16;
        f32x4 acc = {0.f, 0.f, 0.f, 0.f};
#pragma unroll
        for (int kb = 0; kb < 4; ++kb) {
            int ao = (ti0 + l15) * 136 + kb * 32 + lg * 8;
            int bo = (tj0 + l15) * 136 + kb * 32 + lg * 8;
            u32x4 ah = *(const u32x4*)(&Zhi[0][0] + ao);
            u32x4 al = *(const u32x4*)(&Zlo[0][0] + ao);
            u32x4 bh = *(const u32x4*)(&Zhi[0][0] + bo);
            u32x4 bl = *(const u32x4*)(&Zlo[0][0] + bo);
            acc = mfma16(ah, bh, acc);
            acc = mfma16(al, bh, acc);
            acc = mfma16(ah, bl, acc);
        }
#pragma unroll
        for (int r = 0; r < 4; ++r)
            Gb[(size_t)(ti0 + lg * 4 + r) * 64 + tj0 + l15] = acc[r];
    }
}

// ---------------------------------------------------------------------------
// Main persistent kernel: 256 WGs x 16 batch rows, loops t=0..64.
// ---------------------------------------------------------------------------
__launch_bounds__(256)
__global__ void esbn_main(const float* __restrict__ Wi,     // for row 256 (rank-1)
                          const float* __restrict__ blstm,
                          const float* __restrict__ bkw,
                          const float* __restrict__ Wg,
                          const float* __restrict__ bg,
                          const float* __restrict__ Wy,
                          const float* __restrict__ by,
                          const float* __restrict__ confg,
                          const float* __restrict__ confb,
                          const unsigned short* __restrict__ WBhi,
                          const unsigned short* __restrict__ WBlo,
                          const unsigned short* __restrict__ KBhi,
                          const unsigned short* __restrict__ KBlo,
                          const float* __restrict__ G,
                          float* __restrict__ Mk,
                          float* __restrict__ out) {
    __shared__ unsigned short AH[2][16][LDA];
    __shared__ unsigned short AL[2][16][LDA];
    __shared__ float bL[NGATE];
    __shared__ float wi256[NGATE];
    __shared__ float wgL[NH];
    __shared__ float bkwL[NK];
    __shared__ float gL[16];
    __shared__ float kr2L[2][16];

    const int tid = threadIdx.x;
    const int w = tid >> 6, l = tid & 63;
    const int l15 = l & 15, lg = l >> 4;
    const int r0 = blockIdx.x * 16;

    for (int i = tid; i < NGATE; i += 256) { bL[i] = blstm[i]; wi256[i] = Wi[(size_t)256 * 2048 + i]; }
    for (int i = tid; i < NH; i += 256) wgL[i] = Wg[i];
    for (int i = tid; i < NK; i += 256) bkwL[i] = bkw[i];
    {
        unsigned int* p0 = (unsigned int*)&AH[0][0][0];
        unsigned int* p1 = (unsigned int*)&AL[0][0][0];
        for (int i = tid; i < 16 * LDA / 2; i += 256) { p0[i] = 0u; p1[i] = 0u; }
    }
    if (tid < 16) kr2L[0][tid] = 0.f;
    const float gain = confg[0], cbias = confb[0], bgv = bg[0];
    __syncthreads();

    float creg[8][4];
#pragma unroll
    for (int i = 0; i < 8; ++i)
#pragma unroll
        for (int r = 0; r < 4; ++r) creg[i][r] = 0.f;

    int cur = 0;
    for (int t = 0; t <= 64; ++t) {
        const int nxt = cur ^ 1;
        // ---------------- Phase A: gates GEMM (bf16x3) + LSTM pointwise ----
        {
            const unsigned short* ah = &AH[cur][0][0];
            const unsigned short* al = &AL[cur][0][0];
#pragma unroll
            for (int i = 0; i < 8; ++i) {
                const int colh = w * 128 + i * 16 + l15;   // h-col 0..511
                f32x4 acc[4];
#pragma unroll
                for (int q = 0; q < 4; ++q) acc[q] = (f32x4){0.f, 0.f, 0.f, 0.f};
                for (int kb = 0; kb < 24; ++kb) {
                    const int aoff = l15 * LDA + kb * 32 + lg * 8;
                    u32x4 fa_hi = *(const u32x4*)(ah + aoff);
                    u32x4 fa_lo = *(const u32x4*)(al + aoff);
#pragma unroll
                    for (int q = 0; q < 4; ++q) {
                        size_t woff = ((size_t)(kb * 4 + lg) * 2048 + q * 512 + colh) * 8;
                        u32x4 wh = *(const u32x4*)(WBhi + woff);
                        u32x4 wl = *(const u32x4*)(WBlo + woff);
                        acc[q] = mfma16(fa_hi, wh, acc[q]);
                        acc[q] = mfma16(fa_lo, wh, acc[q]);
                        acc[q] = mfma16(fa_hi, wl, acc[q]);
                    }
                }
                float kr2[4];
#pragma unroll
                for (int r = 0; r < 4; ++r) kr2[r] = kr2L[cur][lg * 4 + r];
#pragma unroll
                for (int r = 0; r < 4; ++r) {
                    float iv = acc[0][r] + bL[colh]          + kr2[r] * wi256[colh];
                    float fv = acc[1][r] + bL[512 + colh]    + kr2[r] * wi256[512 + colh];
                    float gv = acc[2][r] + bL[1024 + colh]   + kr2[r] * wi256[1024 + colh];
                    float ov = acc[3][r] + bL[1536 + colh]   + kr2[r] * wi256[1536 + colh];
                    float c = sigm(fv) * creg[i][r] + sigm(iv) * tanh_f(gv);
                    creg[i][r] = c;
                    float h = sigm(ov) * tanh_f(c);
                    unsigned short hh = f2bf(h);
                    unsigned short hl = f2bf(h - bf2f(hh));
                    int row = lg * 4 + r;
                    AH[nxt][row][colh] = hh;
                    AL[nxt][row][colh] = hl;
                }
            }
        }
        __syncthreads();
        if (t < 64) {
            // ------------- Phase B: key_w = h@W_kw + b  (bf16x3); g-dot ----
            const unsigned short* nh = &AH[nxt][0][0];
            const unsigned short* nl = &AL[nxt][0][0];
            for (int u = 0; u < 4; ++u) {
                const int n0 = (w * 4 + u) * 16;
                f32x4 acc = {0.f, 0.f, 0.f, 0.f};
                for (int kb = 0; kb < 16; ++kb) {
                    const int aoff = l15 * LDA + kb * 32 + lg * 8;
                    u32x4 fa_hi = *(const u32x4*)(nh + aoff);
                    u32x4 fa_lo = *(const u32x4*)(nl + aoff);
                    size_t woff = ((size_t)(kb * 4 + lg) * 256 + n0 + l15) * 8;
                    u32x4 wh = *(const u32x4*)(KBhi + woff);
                    u32x4 wl = *(const u32x4*)(KBlo + woff);
                    acc = mfma16(fa_hi, wh, acc);
                    acc = mfma16(fa_lo, wh, acc);
                    acc = mfma16(fa_hi, wl, acc);
                }
                const int col = n0 + l15;
                const float bk = bkwL[col];
#pragma unroll
                for (int r = 0; r < 4; ++r) {
                    int row = lg * 4 + r;
                    Mk[((size_t)(r0 + row) * 64 + t) * 256 + col] = acc[r] + bk;
                }
            }
            {   // g = sigmoid(h @ W_g + b_g); wave w handles rows w*4..w*4+3 (row=lg)
                int row = w * 4 + lg;
                float s = 0.f;
                for (int kk = 0; kk < 32; ++kk) {
                    int k = l15 * 32 + kk;
                    float h = bf2f(nh[row * LDA + k]) + bf2f(nl[row * LDA + k]);
                    s += h * wgL[k];
                }
                s += __shfl_xor(s, 1); s += __shfl_xor(s, 2);
                s += __shfl_xor(s, 4); s += __shfl_xor(s, 8);
                if (l15 == 0) gL[row] = sigm(s + bgv);
            }
            __syncthreads();
            // ------------- Phase C: attention read -> key_r ----------------
            {
                const int row = w * 4 + lg;
                const int b = r0 + row;
                if (t > 0) {
                    const float* Grow = G + ((size_t)b * 64 + t) * 64;
                    float sv[4], ev[4];
                    float m = -1e30f;
#pragma unroll
                    for (int q4 = 0; q4 < 4; ++q4) {
                        int tp = q4 * 16 + l15;
                        sv[q4] = (tp < t) ? Grow[tp] : -1e30f;
                        m = fmaxf(m, sv[q4]);
                    }
                    m = fmaxf(m, __shfl_xor(m, 1)); m = fmaxf(m, __shfl_xor(m, 2));
                    m = fmaxf(m, __shfl_xor(m, 4)); m = fmaxf(m, __shfl_xor(m, 8));
                    float s = 0.f, r256 = 0.f;
#pragma unroll
                    for (int q4 = 0; q4 < 4; ++q4) {
                        int tp = q4 * 16 + l15;
                        if (tp < t) {
                            ev[q4] = __expf(sv[q4] - m);
                            s += ev[q4];
                            r256 += ev[q4] * sigm(gain * sv[q4] + cbias);
                        } else ev[q4] = 0.f;
                    }
                    s += __shfl_xor(s, 1); s += __shfl_xor(s, 2);
                    s += __shfl_xor(s, 4); s += __shfl_xor(s, 8);
                    r256 += __shfl_xor(r256, 1); r256 += __shfl_xor(r256, 2);
                    r256 += __shfl_xor(r256, 4); r256 += __shfl_xor(r256, 8);
                    const float inv = 1.f / s;
                    const float gv = gL[row];
                    if (l15 == 0) kr2L[nxt][row] = gv * r256 * inv;
                    f32x4 a4[4];
#pragma unroll
                    for (int j = 0; j < 4; ++j) a4[j] = (f32x4){0.f, 0.f, 0.f, 0.f};
                    const float* MkB = Mk + (size_t)b * 64 * 256 + l15 * 16;
#pragma unroll
                    for (int q4 = 0; q4 < 4; ++q4) {
                        float wv = ev[q4] * inv;
                        for (int tt = 0; tt < 16; ++tt) {
                            int tp = q4 * 16 + tt;
                            if (tp >= t) break;
                            float wt = __shfl(wv, (l & 48) + tt);
                            const f32x4* p = (const f32x4*)(MkB + (size_t)tp * 256);
                            a4[0] += wt * p[0];
                            a4[1] += wt * p[1];
                            a4[2] += wt * p[2];
                            a4[3] += wt * p[3];
                        }
                    }
#pragma unroll
                    for (int j = 0; j < 16; ++j) {
                        float v = gv * a4[j >> 2][j & 3];
                        unsigned short hh = f2bf(v);
                        unsigned short hl = f2bf(v - bf2f(hh));
                        AH[nxt][row][512 + l15 * 16 + j] = hh;
                        AL[nxt][row][512 + l15 * 16 + j] = hl;
                    }
                } else {
#pragma unroll
                    for (int j = 0; j < 16; ++j) {
                        AH[nxt][row][512 + l15 * 16 + j] = 0;
                        AL[nxt][row][512 + l15 * 16 + j] = 0;
                    }
                    if (l15 == 0) kr2L[nxt][row] = 0.f;
                }
            }
            __syncthreads();
        } else {
            // ------------- Phase Y: out = h @ W_y + b_y --------------------
            const unsigned short* nh = &AH[nxt][0][0];
            const unsigned short* nl = &AL[nxt][0][0];
            const int row = tid >> 4;
            const int c0 = (tid & 15) * 8;
            float accy[8];
#pragma unroll
            for (int j = 0; j < 8; ++j) accy[j] = by[c0 + j];
            for (int k = 0; k < 512; ++k) {
                float h = bf2f(nh[row * LDA + k]) + bf2f(nl[row * LDA + k]);
                const float* wy = Wy + (size_t)k * 128 + c0;
#pragma unroll
                for (int j = 0; j < 8; ++j) accy[j] += h * wy[j];
            }
#pragma unroll
            for (int j = 0; j < 8; ++j) out[(size_t)(r0 + row) * 128 + c0 + j] = accy[j];
        }
        cur ^= 1;
    }
}

// ---------------------------------------------------------------------------
extern "C" void kernel_launch(void* const* d_in, const int* in_sizes, int n_in,
                              void* d_out, int out_size, void* d_ws, size_t ws_size,
                              hipStream_t stream) {
    const float* z   = (const float*)d_in[0];
    const float* Wi  = (const float*)d_in[1];
    const float* Wh  = (const float*)d_in[2];
    const float* bl  = (const float*)d_in[3];
    const float* Wkw = (const float*)d_in[4];
    const float* bkw = (const float*)d_in[5];
    const float* Wg  = (const float*)d_in[6];
    const float* bg  = (const float*)d_in[7];
    const float* Wy  = (const float*)d_in[8];
    const float* by  = (const float*)d_in[9];
    const float* cg  = (const float*)d_in[10];
    const float* cb  = (const float*)d_in[11];

    char* wsb = (char*)d_ws;
    unsigned short* WBhi = (unsigned short*)wsb;                         // 3,145,728 B
    unsigned short* WBlo = WBhi + 768 * 2048;                            // 3,145,728 B
    unsigned short* KBhi = (unsigned short*)(wsb + 6291456);             //   262,144 B
    unsigned short* KBlo = KBhi + 512 * 256;                             //   262,144 B
    float* G  = (float*)(wsb + 6815744);                                 // 67,108,864 B
    float* Mk = (float*)(wsb + 73924608);                                // 268,435,456 B
    float* out = (float*)d_out;

    prep_w<<<832, 256, 0, stream>>>(Wi, Wh, Wkw, WBhi, WBlo, KBhi, KBlo);
    gram_k<<<4096, 256, 0, stream>>>(z, G);
    esbn_main<<<256, 256, 0, stream>>>(Wi, bl, bkw, Wg, bg, Wy, by, cg, cb,
                                       WBhi, WBlo, KBhi, KBlo, G, Mk, out);
}

// Round 2
// 7335.515 us; speedup vs baseline: 7.6863x; 7.6863x over previous
//
#include <hip/hip_runtime.h>

typedef __attribute__((ext_vector_type(8))) __bf16 bf16x8;
typedef __attribute__((ext_vector_type(4))) float f32x4;
typedef __attribute__((ext_vector_type(4))) unsigned int u32x4;
typedef unsigned short ush;

#define AS1 __attribute__((address_space(1)))
#define AS3 __attribute__((address_space(3)))

__device__ __forceinline__ ush f2bf(float f) {
    unsigned int u = __float_as_uint(f);
    return (ush)((u + 0x7fffu + ((u >> 16) & 1u)) >> 16);  // RNE
}
__device__ __forceinline__ float bf2f(ush h) {
    return __uint_as_float(((unsigned int)h) << 16);
}
__device__ __forceinline__ float sigm(float x) { return 1.f / (1.f + __expf(-x)); }
__device__ __forceinline__ float tanh_f(float x) {
    float e = __expf(-2.f * x);
    return (1.f - e) / (1.f + e);
}
__device__ __forceinline__ f32x4 mfma16(u32x4 a, u32x4 b, f32x4 c) {
    return __builtin_amdgcn_mfma_f32_16x16x32_bf16(
        __builtin_bit_cast(bf16x8, a), __builtin_bit_cast(bf16x8, b), c, 0, 0, 0);
}
__device__ __forceinline__ void ld_lds16(const void* g, void* l) {
    __builtin_amdgcn_global_load_lds((const AS1 unsigned int*)g, (AS3 unsigned int*)l, 16, 0, 0);
}

// ---------------------------------------------------------------------------
// prep: build swizzled bf16 hi/lo B-operands.
// Gates W = [W_h(512); W_i rows 0..255] (K=768, N=2048) with column permutation
//   nc = (hcol/16)*64 + gate*16 + (hcol%16)  so each lane owns all 4 gates.
// Layout per (nt,kb,plane): [kg(4)][n(128)][8] ushorts (8KB) = LDS image.
// ---------------------------------------------------------------------------
__global__ __launch_bounds__(256)
void prep_w(const float* __restrict__ Wi, const float* __restrict__ Wh,
            const float* __restrict__ Wkw, const float* __restrict__ bl,
            ush* __restrict__ WBsw, ush* __restrict__ KWsw,
            float* __restrict__ bp, float* __restrict__ wip)
{
    int id = blockIdx.x * 256 + threadIdx.x;
    if (id < 196608) {                       // gates: 96 k-octets x 2048 nc
        int kgo = id >> 11, nc = id & 2047;
        int hg = nc >> 6, rem = nc & 63, gate = rem >> 4, hs = rem & 15;
        int co = gate * 512 + hg * 16 + hs;
        int kb = kgo >> 2, kg = kgo & 3;
        int nt = nc >> 7, n = nc & 127;
        size_t dbase = ((size_t)(nt * 24 + kb) * 2) * 4096 + (size_t)(kg * 128 + n) * 8;
#pragma unroll
        for (int e = 0; e < 8; ++e) {
            int k = kgo * 8 + e;
            float v = (k < 512) ? Wh[(size_t)k * 2048 + co] : Wi[(size_t)(k - 512) * 2048 + co];
            ush h = f2bf(v);
            WBsw[dbase + e] = h;
            WBsw[dbase + 4096 + e] = f2bf(v - bf2f(h));
        }
    } else if (id < 212992) {                // Wkw: 64 k-octets x 256 cols
        int id2 = id - 196608;
        int kgo = id2 >> 8, n256 = id2 & 255;
        int nh = n256 >> 7, n = n256 & 127;
        int kb = kgo >> 2, kg = kgo & 3;
        size_t dbase = ((size_t)(nh * 16 + kb) * 2) * 4096 + (size_t)(kg * 128 + n) * 8;
#pragma unroll
        for (int e = 0; e < 8; ++e) {
            int k = kgo * 8 + e;
            float v = Wkw[(size_t)k * 256 + n256];
            ush h = f2bf(v);
            KWsw[dbase + e] = h;
            KWsw[dbase + 4096 + e] = f2bf(v - bf2f(h));
        }
    } else if (id < 215040) {                // permuted bias + Wi row 256
        int nc = id - 212992;
        int hg = nc >> 6, rem = nc & 63, gate = rem >> 4, hs = rem & 15;
        int co = gate * 512 + hg * 16 + hs;
        bp[nc] = bl[co];
        wip[nc] = Wi[(size_t)256 * 2048 + co];
    }
}

// ---------------------------------------------------------------------------
// gram: packed lower-triangular sim: Gpk[off(i) + b*i + j] = z[b,i].z[b,j], j<i
//       off(i) = 2048*i*(i-1)
// ---------------------------------------------------------------------------
__global__ __launch_bounds__(256)
void gram_k(const float* __restrict__ z, float* __restrict__ Gpk) {
    __shared__ ush Zhi[64][136];
    __shared__ ush Zlo[64][136];
    const int b = blockIdx.x;
    const int tid = threadIdx.x;
    const float* zb = z + (size_t)b * (64 * 128);
    for (int idx = tid; idx < 64 * 128; idx += 256) {
        float v = zb[idx];
        int tt = idx >> 7, kk = idx & 127;
        ush h = f2bf(v);
        Zhi[tt][kk] = h;
        Zlo[tt][kk] = f2bf(v - bf2f(h));
    }
    __syncthreads();
    const int w = tid >> 6, l = tid & 63;
    const int l15 = l & 15, lg = l >> 4;
    const int ti0 = w * 16;
    for (int u = 0; u <= w; ++u) {
        int tj0 = u * 16;
        f32x4 acc = {0.f, 0.f, 0.f, 0.f};
#pragma unroll
        for (int kb = 0; kb < 4; ++kb) {
            int ao = (ti0 + l15) * 136 + kb * 32 + lg * 8;
            int bo = (tj0 + l15) * 136 + kb * 32 + lg * 8;
            u32x4 ah = *(const u32x4*)(&Zhi[0][0] + ao);
            u32x4 al = *(const u32x4*)(&Zlo[0][0] + ao);
            u32x4 bh = *(const u32x4*)(&Zhi[0][0] + bo);
            u32x4 bl = *(const u32x4*)(&Zlo[0][0] + bo);
            acc = mfma16(ah, bh, acc);
            acc = mfma16(al, bh, acc);
            acc = mfma16(ah, bl, acc);
        }
#pragma unroll
        for (int r = 0; r < 4; ++r) {
            int i = ti0 + lg * 4 + r, j = tj0 + l15;
            if (j < i)
                Gpk[(size_t)2048 * i * (i - 1) + (size_t)b * i + j] = acc[r];
        }
    }
}

// ---------------------------------------------------------------------------
// stepA: per-step GEMM. bids 0..63: key_w(t-1) tiles (K=512, write Mk[t-1]).
// bids 64..575: gates tiles 128x128 (K=768) + LSTM pointwise epilogue.
// A operand: Abuf parity t&1 (hi/lo planes). h(t) written to parity (t&1)^1.
// ---------------------------------------------------------------------------
__global__ __launch_bounds__(512, 4)
void stepA(int t,
           const ush* __restrict__ Ahi, const ush* __restrict__ Alo,
           ush* __restrict__ Whi, ush* __restrict__ Wlo,
           const ush* __restrict__ WBsw, const ush* __restrict__ KWsw,
           const float* __restrict__ bp, const float* __restrict__ wip,
           const float* __restrict__ kr2, float* __restrict__ cst,
           float* __restrict__ Mk)
{
    __shared__ ush ALDS[2][2][4096];   // [buf][plane][128 rows x 32 k]
    __shared__ ush BLDS[2][2][4096];   // [buf][plane][kg4 x 128 n x 8]
    const int tid = threadIdx.x;
    const int bid = blockIdx.x;
    const bool iskw = (bid < 64);
    if (iskw && t == 0) return;

    int mt, nsel, NKB;
    const ush* Bb;
    if (iskw) { mt = bid >> 1; nsel = bid & 1; Bb = KWsw + (size_t)nsel * 131072; NKB = 16; }
    else { int g = bid - 64; nsel = g & 15; mt = g >> 4; Bb = WBsw + (size_t)nsel * 196608; NKB = 24; }
    const int r0 = mt * 128;

    const int wv = tid >> 6, l = tid & 63, l15 = l & 15, lg = l >> 4;
    const int wm = wv >> 1, wn = wv & 1;      // wave tile: 32 rows x 64 cols

    // staging: thread -> (row=tid>>2, chunk=tid&3); XOR-swizzled source chunk
    const int srow = tid >> 2, scc = tid & 3;
    const int sswz = (srow & 3) ^ ((srow >> 2) & 1);
    const ush* agh = Ahi + (size_t)(r0 + srow) * 768 + (size_t)(scc ^ sswz) * 8;
    const ush* agl = Alo + (size_t)(r0 + srow) * 768 + (size_t)(scc ^ sswz) * 8;

    f32x4 acc[2][4];
#pragma unroll
    for (int a = 0; a < 2; ++a)
#pragma unroll
        for (int q = 0; q < 4; ++q) acc[a][q] = (f32x4){0.f, 0.f, 0.f, 0.f};

    // prologue: stage kb=0 into buf 0
    ld_lds16(agh, &ALDS[0][0][tid * 8]);
    ld_lds16(agl, &ALDS[0][1][tid * 8]);
    ld_lds16(Bb + tid * 8, &BLDS[0][0][tid * 8]);
    ld_lds16(Bb + 4096 + tid * 8, &BLDS[0][1][tid * 8]);
    __syncthreads();

    const int lgs = lg ^ (l15 & 3) ^ ((l15 >> 2) & 1);  // de-swizzled k-chunk
    const int arow = wm * 32 + l15;
    int buf = 0;
    for (int kb = 0; kb < NKB; ++kb) {
        if (kb + 1 < NKB) {      // T3-minimum: issue next-tile stage first
            int nb = buf ^ 1, kn = kb + 1;
            ld_lds16(agh + kn * 32, &ALDS[nb][0][tid * 8]);
            ld_lds16(agl + kn * 32, &ALDS[nb][1][tid * 8]);
            ld_lds16(Bb + (size_t)kn * 8192 + tid * 8, &BLDS[nb][0][tid * 8]);
            ld_lds16(Bb + (size_t)kn * 8192 + 4096 + tid * 8, &BLDS[nb][1][tid * 8]);
        }
        u32x4 ah[2], al2[2], bh[4], bl2[4];
#pragma unroll
        for (int mf = 0; mf < 2; ++mf) {
            int ao = (arow + mf * 16) * 32 + lgs * 8;
            ah[mf] = *(const u32x4*)&ALDS[buf][0][ao];
            al2[mf] = *(const u32x4*)&ALDS[buf][1][ao];
        }
#pragma unroll
        for (int nf = 0; nf < 4; ++nf) {
            int bo = (lg * 128 + wn * 64 + nf * 16 + l15) * 8;
            bh[nf] = *(const u32x4*)&BLDS[buf][0][bo];
            bl2[nf] = *(const u32x4*)&BLDS[buf][1][bo];
        }
#pragma unroll
        for (int mf = 0; mf < 2; ++mf)
#pragma unroll
            for (int nf = 0; nf < 4; ++nf) {
                acc[mf][nf] = mfma16(ah[mf], bh[nf], acc[mf][nf]);
                acc[mf][nf] = mfma16(al2[mf], bh[nf], acc[mf][nf]);
                acc[mf][nf] = mfma16(ah[mf], bl2[nf], acc[mf][nf]);
            }
        __syncthreads();
        buf ^= 1;
    }

    if (iskw) {
        float* MkT = Mk + (size_t)(t - 1) * 1048576;   // [t][b][k]
#pragma unroll
        for (int mf = 0; mf < 2; ++mf)
#pragma unroll
            for (int nf = 0; nf < 4; ++nf) {
                int colw = nsel * 128 + wn * 64 + nf * 16 + l15;
#pragma unroll
                for (int r = 0; r < 4; ++r) {
                    int row = wm * 32 + mf * 16 + lg * 4 + r;
                    MkT[(size_t)(r0 + row) * 256 + colw] = acc[mf][nf][r];
                }
            }
    } else {
        const int hcol = (nsel * 2 + wn) * 16 + l15;
        const int ncb = nsel * 128 + wn * 64 + l15;
        float bv[4], wv4[4];
#pragma unroll
        for (int g4 = 0; g4 < 4; ++g4) { bv[g4] = bp[ncb + g4 * 16]; wv4[g4] = wip[ncb + g4 * 16]; }
#pragma unroll
        for (int mf = 0; mf < 2; ++mf)
#pragma unroll
            for (int r = 0; r < 4; ++r) {
                const int row = wm * 32 + mf * 16 + lg * 4 + r;
                const size_t b = (size_t)(r0 + row);
                const float k2 = kr2[b];
                float iv = acc[mf][0][r] + bv[0] + k2 * wv4[0];
                float fv = acc[mf][1][r] + bv[1] + k2 * wv4[1];
                float gv = acc[mf][2][r] + bv[2] + k2 * wv4[2];
                float ov = acc[mf][3][r] + bv[3] + k2 * wv4[3];
                float cn = sigm(fv) * cst[b * 512 + hcol] + sigm(iv) * tanh_f(gv);
                cst[b * 512 + hcol] = cn;
                float h = sigm(ov) * tanh_f(cn);
                ush hh = f2bf(h);
                Whi[b * 768 + hcol] = hh;
                Wlo[b * 768 + hcol] = f2bf(h - bf2f(hh));
            }
    }
}

// ---------------------------------------------------------------------------
// stepB: attention for step t (t=1..63). One wave per 4 batch rows.
// Produces key_r(t+1) -> Abuf[(t+1)&1] cols 512.. and kr2.
// ---------------------------------------------------------------------------
__global__ __launch_bounds__(256)
void stepB(int t,
           ush* __restrict__ Ahi, ush* __restrict__ Alo,
           const float* __restrict__ Gpk, const float* __restrict__ Mk,
           const float* __restrict__ Wg, const float* __restrict__ bg,
           const float* __restrict__ bkw,
           const float* __restrict__ cgain, const float* __restrict__ cbias,
           float* __restrict__ kr2)
{
    const int tid = threadIdx.x, l = tid & 63, wv = tid >> 6;
    const float gain = cgain[0], cb = cbias[0], bgv = bg[0];
    const float* Gbase = Gpk + (size_t)2048 * t * (t - 1);
    const f32x4 bk4 = *(const f32x4*)(bkw + l * 4);
    for (int q = 0; q < 4; ++q) {
        const size_t b = (size_t)blockIdx.x * 16 + wv * 4 + q;
        // g = sigmoid(h . Wg + bg)
        u32x4 hv = *(const u32x4*)(Ahi + b * 768 + l * 8);
        u32x4 lv = *(const u32x4*)(Alo + b * 768 + l * 8);
        float gd = 0.f;
#pragma unroll
        for (int j = 0; j < 4; ++j) {
            float h0 = bf2f((ush)(hv[j] & 0xffff)) + bf2f((ush)(lv[j] & 0xffff));
            float h1 = bf2f((ush)(hv[j] >> 16)) + bf2f((ush)(lv[j] >> 16));
            gd += h0 * Wg[l * 8 + j * 2] + h1 * Wg[l * 8 + j * 2 + 1];
        }
#pragma unroll
        for (int o = 1; o < 64; o <<= 1) gd += __shfl_xor(gd, o);
        const float g = sigm(gd + bgv);
        // masked softmax over history (lane = tp)
        const float* Grow = Gbase + b * t;
        float sv = (l < t) ? Grow[l] : -1e30f;
        float m = sv;
#pragma unroll
        for (int o = 1; o < 64; o <<= 1) m = fmaxf(m, __shfl_xor(m, o));
        float e = (l < t) ? __expf(sv - m) : 0.f;
        float ck = sigm(gain * sv + cb);
        float s = e, rc = e * ck;
#pragma unroll
        for (int o = 1; o < 64; o <<= 1) { s += __shfl_xor(s, o); rc += __shfl_xor(rc, o); }
        const float inv = 1.f / s;
        // read = sum_t w[tp] * Mk[tp][b][:]   (lane owns 4 k-cols)
        f32x4 a4 = {0.f, 0.f, 0.f, 0.f};
        const float* Mkb = Mk + b * 256 + l * 4;
#pragma unroll 2
        for (int tp = 0; tp < t; ++tp) {
            float wt = __shfl(e, tp) * inv;
            f32x4 mv = *(const f32x4*)(Mkb + (size_t)tp * 1048576);
            a4 += wt * mv;
        }
        // key_r = g*(read + bkw)  (sum of weights = 1)
#pragma unroll
        for (int j = 0; j < 4; ++j) {
            float v = g * (a4[j] + bk4[j]);
            ush hh = f2bf(v);
            Ahi[b * 768 + 512 + l * 4 + j] = hh;
            Alo[b * 768 + 512 + l * 4 + j] = f2bf(v - bf2f(hh));
        }
        if (l == 0) kr2[b] = g * rc * inv;
    }
}

// ---------------------------------------------------------------------------
// stepY: out = h(64) @ W_y + b_y   (fp32, h from hi+lo planes)
// ---------------------------------------------------------------------------
__global__ __launch_bounds__(256)
void stepY(const ush* __restrict__ Ahi, const ush* __restrict__ Alo,
           const float* __restrict__ Wy, const float* __restrict__ by,
           float* __restrict__ out)
{
    __shared__ float hL[4][512];
    const int tid = threadIdx.x;
    const size_t b0 = (size_t)blockIdx.x * 4;
    for (int i = tid; i < 2048; i += 256) {
        int rr = i >> 9, k = i & 511;
        hL[rr][k] = bf2f(Ahi[(b0 + rr) * 768 + k]) + bf2f(Alo[(b0 + rr) * 768 + k]);
    }
    __syncthreads();
    const int col = tid & 127, rA = tid >> 7;
    float a0 = by[col], a1 = a0;
    for (int k = 0; k < 512; ++k) {
        float wyv = Wy[k * 128 + col];
        a0 += hL[rA][k] * wyv;
        a1 += hL[rA + 2][k] * wyv;
    }
    out[(b0 + rA) * 128 + col] = a0;
    out[(b0 + rA + 2) * 128 + col] = a1;
}

// ---------------------------------------------------------------------------
extern "C" void kernel_launch(void* const* d_in, const int* in_sizes, int n_in,
                              void* d_out, int out_size, void* d_ws, size_t ws_size,
                              hipStream_t stream) {
    const float* z   = (const float*)d_in[0];
    const float* Wi  = (const float*)d_in[1];
    const float* Wh  = (const float*)d_in[2];
    const float* bl  = (const float*)d_in[3];
    const float* Wkw = (const float*)d_in[4];
    const float* bkw = (const float*)d_in[5];
    const float* Wg  = (const float*)d_in[6];
    const float* bg  = (const float*)d_in[7];
    const float* Wy  = (const float*)d_in[8];
    const float* by  = (const float*)d_in[9];
    const float* cg  = (const float*)d_in[10];
    const float* cb  = (const float*)d_in[11];

    char* wsb = (char*)d_ws;
    ush*   WBsw = (ush*)(wsb + 0);             //  6,291,456
    ush*   KWsw = (ush*)(wsb + 6291456);       //    524,288
    float* bp   = (float*)(wsb + 6815744);     //      8,192
    float* wip  = (float*)(wsb + 6823936);     //      8,192
    float* kr2  = (float*)(wsb + 6832128);     //     16,384
    float* cst  = (float*)(wsb + 6848512);     //  8,388,608
    ush*   Abuf = (ush*)(wsb + 15237120);      // 25,165,824 (2 par x 2 pl x 6,291,456/2)
    float* Gpk  = (float*)(wsb + 40402944);    // 33,030,144
    float* Mk   = (float*)(wsb + 73433088);    // 268,435,456  (end 341,868,544)
    float* out  = (float*)d_out;

    hipMemsetAsync(Abuf, 0, 25165824, stream);
    hipMemsetAsync(cst, 0, 8388608, stream);
    hipMemsetAsync(kr2, 0, 16384, stream);

    prep_w<<<840, 256, 0, stream>>>(Wi, Wh, Wkw, bl, WBsw, KWsw, bp, wip);
    gram_k<<<4096, 256, 0, stream>>>(z, Gpk);

    auto Ap = [&](int par, int pl) { return Abuf + ((size_t)par * 2 + pl) * 3145728; };

    for (int t = 0; t <= 64; ++t) {
        int pr = t & 1;
        stepA<<<576, 512, 0, stream>>>(t, Ap(pr, 0), Ap(pr, 1), Ap(pr ^ 1, 0), Ap(pr ^ 1, 1),
                                       WBsw, KWsw, bp, wip, kr2, cst, Mk);
        if (t >= 1 && t < 64)
            stepB<<<256, 256, 0, stream>>>(t, Ap(pr ^ 1, 0), Ap(pr ^ 1, 1), Gpk, Mk,
                                           Wg, bg, bkw, cg, cb, kr2);
    }
    stepY<<<1024, 256, 0, stream>>>(Ap(1, 0), Ap(1, 1), Wy, by, out);
}

// Round 3
// 5512.336 us; speedup vs baseline: 10.2285x; 1.3307x over previous
//
#include <hip/hip_runtime.h>

typedef __attribute__((ext_vector_type(8))) __bf16 bf16x8;
typedef __attribute__((ext_vector_type(4))) float f32x4;
typedef __attribute__((ext_vector_type(4))) unsigned int u32x4;
typedef unsigned short ush;

#define AS1 __attribute__((address_space(1)))
#define AS3 __attribute__((address_space(3)))

__device__ __forceinline__ ush f2bf(float f) {
    unsigned int u = __float_as_uint(f);
    return (ush)((u + 0x7fffu + ((u >> 16) & 1u)) >> 16);  // RNE
}
__device__ __forceinline__ float bf2f(ush h) {
    return __uint_as_float(((unsigned int)h) << 16);
}
__device__ __forceinline__ float sigm(float x) { return 1.f / (1.f + __expf(-x)); }
__device__ __forceinline__ float tanh_f(float x) {
    float e = __expf(-2.f * x);
    return (1.f - e) / (1.f + e);
}
__device__ __forceinline__ f32x4 mfma16(u32x4 a, u32x4 b, f32x4 c) {
    return __builtin_amdgcn_mfma_f32_16x16x32_bf16(
        __builtin_bit_cast(bf16x8, a), __builtin_bit_cast(bf16x8, b), c, 0, 0, 0);
}
__device__ __forceinline__ void ld_lds16(const void* g, void* l) {
    __builtin_amdgcn_global_load_lds((const AS1 unsigned int*)g, (AS3 unsigned int*)l, 16, 0, 0);
}

// ---------------------------------------------------------------------------
// prep: build swizzled bf16 hi/lo B-operands.
// Gates W = [W_h(512); W_i rows 0..255] (K=768, N=2048) with column permutation
//   nc = (hcol/16)*64 + gate*16 + (hcol%16)  so each lane owns all 4 gates.
// Layout per (nt,kb,plane): [kg(4)][n(128)][8] ushorts (8KB) = LDS image.
// ---------------------------------------------------------------------------
__global__ __launch_bounds__(256)
void prep_w(const float* __restrict__ Wi, const float* __restrict__ Wh,
            const float* __restrict__ Wkw, const float* __restrict__ bl,
            ush* __restrict__ WBsw, ush* __restrict__ KWsw,
            float* __restrict__ bp, float* __restrict__ wip)
{
    int id = blockIdx.x * 256 + threadIdx.x;
    if (id < 196608) {                       // gates: 96 k-octets x 2048 nc
        int kgo = id >> 11, nc = id & 2047;
        int hg = nc >> 6, rem = nc & 63, gate = rem >> 4, hs = rem & 15;
        int co = gate * 512 + hg * 16 + hs;
        int kb = kgo >> 2, kg = kgo & 3;
        int nt = nc >> 7, n = nc & 127;
        size_t dbase = ((size_t)(nt * 24 + kb) * 2) * 4096 + (size_t)(kg * 128 + n) * 8;
#pragma unroll
        for (int e = 0; e < 8; ++e) {
            int k = kgo * 8 + e;
            float v = (k < 512) ? Wh[(size_t)k * 2048 + co] : Wi[(size_t)(k - 512) * 2048 + co];
            ush h = f2bf(v);
            WBsw[dbase + e] = h;
            WBsw[dbase + 4096 + e] = f2bf(v - bf2f(h));
        }
    } else if (id < 212992) {                // Wkw: 64 k-octets x 256 cols
        int id2 = id - 196608;
        int kgo = id2 >> 8, n256 = id2 & 255;
        int nh = n256 >> 7, n = n256 & 127;
        int kb = kgo >> 2, kg = kgo & 3;
        size_t dbase = ((size_t)(nh * 16 + kb) * 2) * 4096 + (size_t)(kg * 128 + n) * 8;
#pragma unroll
        for (int e = 0; e < 8; ++e) {
            int k = kgo * 8 + e;
            float v = Wkw[(size_t)k * 256 + n256];
            ush h = f2bf(v);
            KWsw[dbase + e] = h;
            KWsw[dbase + 4096 + e] = f2bf(v - bf2f(h));
        }
    } else if (id < 215040) {                // permuted bias + Wi row 256
        int nc = id - 212992;
        int hg = nc >> 6, rem = nc & 63, gate = rem >> 4, hs = rem & 15;
        int co = gate * 512 + hg * 16 + hs;
        bp[nc] = bl[co];
        wip[nc] = Wi[(size_t)256 * 2048 + co];
    }
}

// ---------------------------------------------------------------------------
// gram: packed lower-triangular sim: Gpk[off(i) + b*i + j] = z[b,i].z[b,j], j<i
//       off(i) = 2048*i*(i-1)
// ---------------------------------------------------------------------------
__global__ __launch_bounds__(256)
void gram_k(const float* __restrict__ z, float* __restrict__ Gpk) {
    __shared__ ush Zhi[64][136];
    __shared__ ush Zlo[64][136];
    const int b = blockIdx.x;
    const int tid = threadIdx.x;
    const float* zb = z + (size_t)b * (64 * 128);
    for (int idx = tid; idx < 64 * 128; idx += 256) {
        float v = zb[idx];
        int tt = idx >> 7, kk = idx & 127;
        ush h = f2bf(v);
        Zhi[tt][kk] = h;
        Zlo[tt][kk] = f2bf(v - bf2f(h));
    }
    __syncthreads();
    const int w = tid >> 6, l = tid & 63;
    const int l15 = l & 15, lg = l >> 4;
    const int ti0 = w * 16;
    for (int u = 0; u <= w; ++u) {
        int tj0 = u * 16;
        f32x4 acc = {0.f, 0.f, 0.f, 0.f};
#pragma unroll
        for (int kb = 0; kb < 4; ++kb) {
            int ao = (ti0 + l15) * 136 + kb * 32 + lg * 8;
            int bo = (tj0 + l15) * 136 + kb * 32 + lg * 8;
            u32x4 ah = *(const u32x4*)(&Zhi[0][0] + ao);
            u32x4 al = *(const u32x4*)(&Zlo[0][0] + ao);
            u32x4 bh = *(const u32x4*)(&Zhi[0][0] + bo);
            u32x4 bl = *(const u32x4*)(&Zlo[0][0] + bo);
            acc = mfma16(ah, bh, acc);
            acc = mfma16(al, bh, acc);
            acc = mfma16(ah, bl, acc);
        }
#pragma unroll
        for (int r = 0; r < 4; ++r) {
            int i = ti0 + lg * 4 + r, j = tj0 + l15;
            if (j < i)
                Gpk[(size_t)2048 * i * (i - 1) + (size_t)b * i + j] = acc[r];
        }
    }
}

// ---------------------------------------------------------------------------
// stepA: per-step GEMM. bids 0..63: key_w(t-1) tiles (K=512, write Mk[t-1]).
// bids 64..575: gates tiles 128x128 (K=768) + LSTM pointwise epilogue.
// A operand: Abuf parity t&1 (hi/lo planes). h(t) written to parity (t&1)^1.
// Mk layout: [b][t][k]  (b-major, per-b history contiguous 64KB)
// ---------------------------------------------------------------------------
__global__ __launch_bounds__(512, 4)
void stepA(int t,
           const ush* __restrict__ Ahi, const ush* __restrict__ Alo,
           ush* __restrict__ Whi, ush* __restrict__ Wlo,
           const ush* __restrict__ WBsw, const ush* __restrict__ KWsw,
           const float* __restrict__ bp, const float* __restrict__ wip,
           const float* __restrict__ kr2, float* __restrict__ cst,
           float* __restrict__ Mk)
{
    __shared__ ush ALDS[2][2][4096];   // [buf][plane][128 rows x 32 k]
    __shared__ ush BLDS[2][2][4096];   // [buf][plane][kg4 x 128 n x 8]
    const int tid = threadIdx.x;
    const int bid = blockIdx.x;
    const bool iskw = (bid < 64);
    if (iskw && t == 0) return;

    int mt, nsel, NKB;
    const ush* Bb;
    if (iskw) { mt = bid >> 1; nsel = bid & 1; Bb = KWsw + (size_t)nsel * 131072; NKB = 16; }
    else { int g = bid - 64; nsel = g & 15; mt = g >> 4; Bb = WBsw + (size_t)nsel * 196608; NKB = 24; }
    const int r0 = mt * 128;

    const int wv = tid >> 6, l = tid & 63, l15 = l & 15, lg = l >> 4;
    const int wm = wv >> 1, wn = wv & 1;      // wave tile: 32 rows x 64 cols

    // staging: thread -> (row=tid>>2, chunk=tid&3); XOR-swizzled source chunk
    const int srow = tid >> 2, scc = tid & 3;
    const int sswz = (srow & 3) ^ ((srow >> 2) & 1);
    const ush* agh = Ahi + (size_t)(r0 + srow) * 768 + (size_t)(scc ^ sswz) * 8;
    const ush* agl = Alo + (size_t)(r0 + srow) * 768 + (size_t)(scc ^ sswz) * 8;

    f32x4 acc[2][4];
#pragma unroll
    for (int a = 0; a < 2; ++a)
#pragma unroll
        for (int q = 0; q < 4; ++q) acc[a][q] = (f32x4){0.f, 0.f, 0.f, 0.f};

    // prologue: stage kb=0 into buf 0
    ld_lds16(agh, &ALDS[0][0][tid * 8]);
    ld_lds16(agl, &ALDS[0][1][tid * 8]);
    ld_lds16(Bb + tid * 8, &BLDS[0][0][tid * 8]);
    ld_lds16(Bb + 4096 + tid * 8, &BLDS[0][1][tid * 8]);
    __syncthreads();

    const int lgs = lg ^ (l15 & 3) ^ ((l15 >> 2) & 1);  // de-swizzled k-chunk
    const int arow = wm * 32 + l15;
    int buf = 0;
    for (int kb = 0; kb < NKB; ++kb) {
        if (kb + 1 < NKB) {      // T3-minimum: issue next-tile stage first
            int nb = buf ^ 1, kn = kb + 1;
            ld_lds16(agh + kn * 32, &ALDS[nb][0][tid * 8]);
            ld_lds16(agl + kn * 32, &ALDS[nb][1][tid * 8]);
            ld_lds16(Bb + (size_t)kn * 8192 + tid * 8, &BLDS[nb][0][tid * 8]);
            ld_lds16(Bb + (size_t)kn * 8192 + 4096 + tid * 8, &BLDS[nb][1][tid * 8]);
        }
        u32x4 ah[2], al2[2], bh[4], bl2[4];
#pragma unroll
        for (int mf = 0; mf < 2; ++mf) {
            int ao = (arow + mf * 16) * 32 + lgs * 8;
            ah[mf] = *(const u32x4*)&ALDS[buf][0][ao];
            al2[mf] = *(const u32x4*)&ALDS[buf][1][ao];
        }
#pragma unroll
        for (int nf = 0; nf < 4; ++nf) {
            int bo = (lg * 128 + wn * 64 + nf * 16 + l15) * 8;
            bh[nf] = *(const u32x4*)&BLDS[buf][0][bo];
            bl2[nf] = *(const u32x4*)&BLDS[buf][1][bo];
        }
#pragma unroll
        for (int mf = 0; mf < 2; ++mf)
#pragma unroll
            for (int nf = 0; nf < 4; ++nf) {
                acc[mf][nf] = mfma16(ah[mf], bh[nf], acc[mf][nf]);
                acc[mf][nf] = mfma16(al2[mf], bh[nf], acc[mf][nf]);
                acc[mf][nf] = mfma16(ah[mf], bl2[nf], acc[mf][nf]);
            }
        __syncthreads();
        buf ^= 1;
    }

    if (iskw) {
#pragma unroll
        for (int mf = 0; mf < 2; ++mf)
#pragma unroll
            for (int nf = 0; nf < 4; ++nf) {
                int colw = nsel * 128 + wn * 64 + nf * 16 + l15;
#pragma unroll
                for (int r = 0; r < 4; ++r) {
                    int row = wm * 32 + mf * 16 + lg * 4 + r;
                    Mk[((size_t)(r0 + row) * 64 + (t - 1)) * 256 + colw] = acc[mf][nf][r];
                }
            }
    } else {
        const int hcol = (nsel * 2 + wn) * 16 + l15;
        const int ncb = nsel * 128 + wn * 64 + l15;
        float bv[4], wv4[4];
#pragma unroll
        for (int g4 = 0; g4 < 4; ++g4) { bv[g4] = bp[ncb + g4 * 16]; wv4[g4] = wip[ncb + g4 * 16]; }
#pragma unroll
        for (int mf = 0; mf < 2; ++mf)
#pragma unroll
            for (int r = 0; r < 4; ++r) {
                const int row = wm * 32 + mf * 16 + lg * 4 + r;
                const size_t b = (size_t)(r0 + row);
                const float k2 = kr2[b];
                float iv = acc[mf][0][r] + bv[0] + k2 * wv4[0];
                float fv = acc[mf][1][r] + bv[1] + k2 * wv4[1];
                float gv = acc[mf][2][r] + bv[2] + k2 * wv4[2];
                float ov = acc[mf][3][r] + bv[3] + k2 * wv4[3];
                float cn = sigm(fv) * cst[b * 512 + hcol] + sigm(iv) * tanh_f(gv);
                cst[b * 512 + hcol] = cn;
                float h = sigm(ov) * tanh_f(cn);
                ush hh = f2bf(h);
                Whi[b * 768 + hcol] = hh;
                Wlo[b * 768 + hcol] = f2bf(h - bf2f(hh));
            }
    }
}

// ---------------------------------------------------------------------------
// stepB: attention read for step t (t=1..63). ONE BLOCK PER BATCH ROW b.
// 4 waves tp-interleaved over the contiguous Mk[b][0..t-1][:] history;
// each wave-iteration streams one full 1KB row (lane-wide f32x4).
// Produces key_r(t+1) -> Abuf[(t+1)&1] cols 512.. and kr2.
// ---------------------------------------------------------------------------
__global__ __launch_bounds__(256)
void stepB(int t,
           ush* __restrict__ Ahi, ush* __restrict__ Alo,
           const float* __restrict__ Gpk, const float* __restrict__ Mk,
           const float* __restrict__ Wg, const float* __restrict__ bg,
           const float* __restrict__ bkw,
           const float* __restrict__ cgain, const float* __restrict__ cbias,
           float* __restrict__ kr2)
{
    __shared__ float wrow[64];
    __shared__ float SAcc[4][256];
    __shared__ float red[4];
    __shared__ float rcg;
    const int tid = threadIdx.x, l = tid & 63, w = tid >> 6;
    const size_t b = blockIdx.x;

    // ---- g partial: thread owns h-cols tid*2, tid*2+1
    {
        unsigned int hv = *(const unsigned int*)(Ahi + b * 768 + tid * 2);
        unsigned int lv = *(const unsigned int*)(Alo + b * 768 + tid * 2);
        float h0 = bf2f((ush)(hv & 0xffffu)) + bf2f((ush)(lv & 0xffffu));
        float h1 = bf2f((ush)(hv >> 16)) + bf2f((ush)(lv >> 16));
        float p = h0 * Wg[tid * 2] + h1 * Wg[tid * 2 + 1];
#pragma unroll
        for (int o = 1; o < 64; o <<= 1) p += __shfl_xor(p, o);
        if (l == 0) red[w] = p;
    }
    // ---- wave 0: masked softmax over history + confidence scalar
    if (w == 0) {
        const float* Grow = Gpk + (size_t)2048 * t * (t - 1) + b * t;
        float sv = (l < t) ? Grow[l] : -1e30f;
        float m = sv;
#pragma unroll
        for (int o = 1; o < 64; o <<= 1) m = fmaxf(m, __shfl_xor(m, o));
        float e = (l < t) ? __expf(sv - m) : 0.f;
        float ck = sigm(cgain[0] * sv + cbias[0]);
        float s = e, rc = e * ck;
#pragma unroll
        for (int o = 1; o < 64; o <<= 1) { s += __shfl_xor(s, o); rc += __shfl_xor(rc, o); }
        float inv = 1.f / s;
        wrow[l] = e * inv;
        if (l == 0) rcg = rc * inv;
    }
    __syncthreads();
    const float g = sigm(red[0] + red[1] + red[2] + red[3] + bg[0]);

    // ---- gather: wave w handles tp = w, w+4, ...; lane owns k-cols l*4..l*4+3
    f32x4 acc = {0.f, 0.f, 0.f, 0.f};
    const f32x4* Mkb = (const f32x4*)(Mk + b * 16384) + l;   // [b][tp][l*4]
#pragma unroll 4
    for (int tp = w; tp < t; tp += 4)
        acc += wrow[tp] * Mkb[(size_t)tp * 64];
    *(f32x4*)&SAcc[w][l * 4] = acc;
    __syncthreads();

    // ---- final: thread owns col tid
    float sum = SAcc[0][tid] + SAcc[1][tid] + SAcc[2][tid] + SAcc[3][tid];
    float v = g * (sum + bkw[tid]);   // bias folded post-sum (softmax weights sum to 1)
    ush hh = f2bf(v);
    Ahi[b * 768 + 512 + tid] = hh;
    Alo[b * 768 + 512 + tid] = f2bf(v - bf2f(hh));
    if (tid == 0) kr2[b] = g * rcg;
}

// ---------------------------------------------------------------------------
// stepY: out = h(64) @ W_y + b_y   (fp32, h from hi+lo planes)
// ---------------------------------------------------------------------------
__global__ __launch_bounds__(256)
void stepY(const ush* __restrict__ Ahi, const ush* __restrict__ Alo,
           const float* __restrict__ Wy, const float* __restrict__ by,
           float* __restrict__ out)
{
    __shared__ float hL[4][512];
    const int tid = threadIdx.x;
    const size_t b0 = (size_t)blockIdx.x * 4;
    for (int i = tid; i < 2048; i += 256) {
        int rr = i >> 9, k = i & 511;
        hL[rr][k] = bf2f(Ahi[(b0 + rr) * 768 + k]) + bf2f(Alo[(b0 + rr) * 768 + k]);
    }
    __syncthreads();
    const int col = tid & 127, rA = tid >> 7;
    float a0 = by[col], a1 = a0;
    for (int k = 0; k < 512; ++k) {
        float wyv = Wy[k * 128 + col];
        a0 += hL[rA][k] * wyv;
        a1 += hL[rA + 2][k] * wyv;
    }
    out[(b0 + rA) * 128 + col] = a0;
    out[(b0 + rA + 2) * 128 + col] = a1;
}

// ---------------------------------------------------------------------------
extern "C" void kernel_launch(void* const* d_in, const int* in_sizes, int n_in,
                              void* d_out, int out_size, void* d_ws, size_t ws_size,
                              hipStream_t stream) {
    const float* z   = (const float*)d_in[0];
    const float* Wi  = (const float*)d_in[1];
    const float* Wh  = (const float*)d_in[2];
    const float* bl  = (const float*)d_in[3];
    const float* Wkw = (const float*)d_in[4];
    const float* bkw = (const float*)d_in[5];
    const float* Wg  = (const float*)d_in[6];
    const float* bg  = (const float*)d_in[7];
    const float* Wy  = (const float*)d_in[8];
    const float* by  = (const float*)d_in[9];
    const float* cg  = (const float*)d_in[10];
    const float* cb  = (const float*)d_in[11];

    char* wsb = (char*)d_ws;
    ush*   WBsw = (ush*)(wsb + 0);             //  6,291,456
    ush*   KWsw = (ush*)(wsb + 6291456);       //    524,288
    float* bp   = (float*)(wsb + 6815744);     //      8,192
    float* wip  = (float*)(wsb + 6823936);     //      8,192
    float* kr2  = (float*)(wsb + 6832128);     //     16,384
    float* cst  = (float*)(wsb + 6848512);     //  8,388,608
    ush*   Abuf = (ush*)(wsb + 15237120);      // 25,165,824 (2 par x 2 pl x 6,291,456/2)
    float* Gpk  = (float*)(wsb + 40402944);    // 33,030,144
    float* Mk   = (float*)(wsb + 73433088);    // 268,435,456  [b][t][k]
    float* out  = (float*)d_out;

    hipMemsetAsync(Abuf, 0, 25165824, stream);
    hipMemsetAsync(cst, 0, 8388608, stream);
    hipMemsetAsync(kr2, 0, 16384, stream);

    prep_w<<<840, 256, 0, stream>>>(Wi, Wh, Wkw, bl, WBsw, KWsw, bp, wip);
    gram_k<<<4096, 256, 0, stream>>>(z, Gpk);

    auto Ap = [&](int par, int pl) { return Abuf + ((size_t)par * 2 + pl) * 3145728; };

    for (int t = 0; t <= 64; ++t) {
        int pr = t & 1;
        stepA<<<576, 512, 0, stream>>>(t, Ap(pr, 0), Ap(pr, 1), Ap(pr ^ 1, 0), Ap(pr ^ 1, 1),
                                       WBsw, KWsw, bp, wip, kr2, cst, Mk);
        if (t >= 1 && t < 64)
            stepB<<<4096, 256, 0, stream>>>(t, Ap(pr ^ 1, 0), Ap(pr ^ 1, 1), Gpk, Mk,
                                            Wg, bg, bkw, cg, cb, kr2);
    }
    stepY<<<1024, 256, 0, stream>>>(Ap(1, 0), Ap(1, 1), Wy, by, out);
}

// Round 4
// 4305.580 us; speedup vs baseline: 13.0954x; 1.2803x over previous
//
#include <hip/hip_runtime.h>

typedef __attribute__((ext_vector_type(8))) __bf16 bf16x8;
typedef __attribute__((ext_vector_type(4))) float f32x4;
typedef __attribute__((ext_vector_type(4))) unsigned int u32x4;
typedef unsigned short ush;
typedef _Float16 f16;
typedef __attribute__((ext_vector_type(4))) _Float16 f16x4;

#define AS1 __attribute__((address_space(1)))
#define AS3 __attribute__((address_space(3)))

__device__ __forceinline__ ush f2bf(float f) {
    unsigned int u = __float_as_uint(f);
    return (ush)((u + 0x7fffu + ((u >> 16) & 1u)) >> 16);  // RNE
}
__device__ __forceinline__ float bf2f(ush h) {
    return __uint_as_float(((unsigned int)h) << 16);
}
__device__ __forceinline__ float sigm(float x) { return 1.f / (1.f + __expf(-x)); }
__device__ __forceinline__ float tanh_f(float x) {
    float e = __expf(-2.f * x);
    return (1.f - e) / (1.f + e);
}
__device__ __forceinline__ f32x4 mfma16(u32x4 a, u32x4 b, f32x4 c) {
    return __builtin_amdgcn_mfma_f32_16x16x32_bf16(
        __builtin_bit_cast(bf16x8, a), __builtin_bit_cast(bf16x8, b), c, 0, 0, 0);
}
__device__ __forceinline__ void ld_lds16(const void* g, void* l) {
    __builtin_amdgcn_global_load_lds((const AS1 unsigned int*)g, (AS3 unsigned int*)l, 16, 0, 0);
}

// ---------------------------------------------------------------------------
// prep: swizzled bf16 hi/lo B-operands (unchanged layout from round 3).
// ---------------------------------------------------------------------------
__global__ __launch_bounds__(256)
void prep_w(const float* __restrict__ Wi, const float* __restrict__ Wh,
            const float* __restrict__ Wkw, const float* __restrict__ bl,
            ush* __restrict__ WBsw, ush* __restrict__ KWsw,
            float* __restrict__ bp, float* __restrict__ wip)
{
    int id = blockIdx.x * 256 + threadIdx.x;
    if (id < 196608) {                       // gates: 96 k-octets x 2048 nc
        int kgo = id >> 11, nc = id & 2047;
        int hg = nc >> 6, rem = nc & 63, gate = rem >> 4, hs = rem & 15;
        int co = gate * 512 + hg * 16 + hs;
        int kb = kgo >> 2, kg = kgo & 3;
        int nt = nc >> 7, n = nc & 127;
        size_t dbase = ((size_t)(nt * 24 + kb) * 2) * 4096 + (size_t)(kg * 128 + n) * 8;
#pragma unroll
        for (int e = 0; e < 8; ++e) {
            int k = kgo * 8 + e;
            float v = (k < 512) ? Wh[(size_t)k * 2048 + co] : Wi[(size_t)(k - 512) * 2048 + co];
            ush h = f2bf(v);
            WBsw[dbase + e] = h;
            WBsw[dbase + 4096 + e] = f2bf(v - bf2f(h));
        }
    } else if (id < 212992) {                // Wkw: 64 k-octets x 256 cols
        int id2 = id - 196608;
        int kgo = id2 >> 8, n256 = id2 & 255;
        int nh = n256 >> 7, n = n256 & 127;
        int kb = kgo >> 2, kg = kgo & 3;
        size_t dbase = ((size_t)(nh * 16 + kb) * 2) * 4096 + (size_t)(kg * 128 + n) * 8;
#pragma unroll
        for (int e = 0; e < 8; ++e) {
            int k = kgo * 8 + e;
            float v = Wkw[(size_t)k * 256 + n256];
            ush h = f2bf(v);
            KWsw[dbase + e] = h;
            KWsw[dbase + 4096 + e] = f2bf(v - bf2f(h));
        }
    } else if (id < 215040) {                // permuted bias + Wi row 256
        int nc = id - 212992;
        int hg = nc >> 6, rem = nc & 63, gate = rem >> 4, hs = rem & 15;
        int co = gate * 512 + hg * 16 + hs;
        bp[nc] = bl[co];
        wip[nc] = Wi[(size_t)256 * 2048 + co];
    }
}

// ---------------------------------------------------------------------------
// gram: packed lower-triangular sims (unchanged).
// ---------------------------------------------------------------------------
__global__ __launch_bounds__(256)
void gram_k(const float* __restrict__ z, float* __restrict__ Gpk) {
    __shared__ ush Zhi[64][136];
    __shared__ ush Zlo[64][136];
    const int b = blockIdx.x;
    const int tid = threadIdx.x;
    const float* zb = z + (size_t)b * (64 * 128);
    for (int idx = tid; idx < 64 * 128; idx += 256) {
        float v = zb[idx];
        int tt = idx >> 7, kk = idx & 127;
        ush h = f2bf(v);
        Zhi[tt][kk] = h;
        Zlo[tt][kk] = f2bf(v - bf2f(h));
    }
    __syncthreads();
    const int w = tid >> 6, l = tid & 63;
    const int l15 = l & 15, lg = l >> 4;
    const int ti0 = w * 16;
    for (int u = 0; u <= w; ++u) {
        int tj0 = u * 16;
        f32x4 acc = {0.f, 0.f, 0.f, 0.f};
#pragma unroll
        for (int kb = 0; kb < 4; ++kb) {
            int ao = (ti0 + l15) * 136 + kb * 32 + lg * 8;
            int bo = (tj0 + l15) * 136 + kb * 32 + lg * 8;
            u32x4 ah = *(const u32x4*)(&Zhi[0][0] + ao);
            u32x4 al = *(const u32x4*)(&Zlo[0][0] + ao);
            u32x4 bh = *(const u32x4*)(&Zhi[0][0] + bo);
            u32x4 bl = *(const u32x4*)(&Zlo[0][0] + bo);
            acc = mfma16(ah, bh, acc);
            acc = mfma16(al, bh, acc);
            acc = mfma16(ah, bl, acc);
        }
#pragma unroll
        for (int r = 0; r < 4; ++r) {
            int i = ti0 + lg * 4 + r, j = tj0 + l15;
            if (j < i)
                Gpk[(size_t)2048 * i * (i - 1) + (size_t)b * i + j] = acc[r];
        }
    }
}

// ---------------------------------------------------------------------------
// D1 (stepA): one dispatch per step, three roles:
//  bid<512 : gates 128x128 tile (K=768, 3-pass) + FUSED key_w 128x16 slice
//            (K=512, B-frags streamed from L2) + LSTM epilogue.
//  bid>=512: B1 attention partial (softmax from Gram + gather over tp<=t-2,
//            fp16 Mk) -> readp/wlast/rcb.  2 rows per block.
// ---------------------------------------------------------------------------
__global__ __launch_bounds__(512, 4)
void stepA(int t,
           const ush* __restrict__ Ahi, const ush* __restrict__ Alo,
           ush* __restrict__ Whi, ush* __restrict__ Wlo,
           const ush* __restrict__ WBsw, const ush* __restrict__ KWsw,
           const float* __restrict__ bp, const float* __restrict__ wip,
           const float* __restrict__ kr2, float* __restrict__ cst,
           f16* __restrict__ Mk16,
           const float* __restrict__ Gpk,
           float* __restrict__ readp, float* __restrict__ wlast,
           float* __restrict__ rcb,
           const float* __restrict__ cgain, const float* __restrict__ cbias)
{
    __shared__ ush ALDS[2][2][4096];
    __shared__ ush BLDS[2][2][4096];
    __shared__ float wrowL[2][64];
    __shared__ float SAccL[2][4][256];

    const int tid = threadIdx.x;
    const int bid = blockIdx.x;

    if (bid >= 512) {
        // ================= B1 role =================
        if (t < 1 || t >= 64) return;
        const int half = tid >> 8, tid2 = tid & 255;
        const int l = tid2 & 63, w4 = tid2 >> 6;
        const size_t b = (size_t)(bid - 512) * 2 + half;
        if (w4 == 0) {
            const float* Grow = Gpk + (size_t)2048 * t * (t - 1) + b * t;
            float sv = (l < t) ? Grow[l] : -1e30f;
            float m = sv;
#pragma unroll
            for (int o = 1; o < 64; o <<= 1) m = fmaxf(m, __shfl_xor(m, o));
            float e = (l < t) ? __expf(sv - m) : 0.f;
            float ck = sigm(cgain[0] * sv + cbias[0]);
            float s = e, rc = e * ck;
#pragma unroll
            for (int o = 1; o < 64; o <<= 1) { s += __shfl_xor(s, o); rc += __shfl_xor(rc, o); }
            float inv = 1.f / s;
            wrowL[half][l] = e * inv;
            if (l == 0) rcb[b] = rc * inv;
        }
        __syncthreads();
        f32x4 acc = {0.f, 0.f, 0.f, 0.f};
        const f16* Mkb = Mk16 + b * 16384 + l * 4;
#pragma unroll 4
        for (int tp = w4; tp < t - 1; tp += 4) {
            f16x4 mv = *(const f16x4*)(Mkb + (size_t)tp * 256);
            float wt = wrowL[half][tp];
            acc[0] += wt * (float)mv[0];
            acc[1] += wt * (float)mv[1];
            acc[2] += wt * (float)mv[2];
            acc[3] += wt * (float)mv[3];
        }
        *(f32x4*)&SAccL[half][w4][l * 4] = acc;
        __syncthreads();
        float sum = SAccL[half][0][tid2] + SAccL[half][1][tid2]
                  + SAccL[half][2][tid2] + SAccL[half][3][tid2];
        readp[b * 256 + tid2] = sum;
        if (tid2 == 0) wlast[b] = wrowL[half][t - 1];
        return;
    }

    // ================= gates + fused kw role =================
    const int nsel = bid & 15, mt = bid >> 4;
    const int r0 = mt * 128;
    const ush* Bb = WBsw + (size_t)nsel * 196608;
    const bool dokw = (t >= 1 && t <= 63);

    const int wv = tid >> 6, l = tid & 63, l15 = l & 15, lg = l >> 4;
    const int wm = wv >> 1, wn = wv & 1;      // wave tile: 32 rows x 64 cols

    // kw: this block owns cols nsel*16..+15; wave wv owns rows wv*16..+15
    const int kwcol = nsel * 16 + l15;
    const ush* KWb = KWsw + (size_t)(kwcol >> 7) * 131072;
    const int kwn = kwcol & 127;

    // staging: thread -> (row=tid>>2, chunk=tid&3); XOR-swizzled source chunk
    const int srow = tid >> 2, scc = tid & 3;
    const int sswz = (srow & 3) ^ ((srow >> 2) & 1);
    const ush* agh = Ahi + (size_t)(r0 + srow) * 768 + (size_t)(scc ^ sswz) * 8;
    const ush* agl = Alo + (size_t)(r0 + srow) * 768 + (size_t)(scc ^ sswz) * 8;

    f32x4 acc[2][4];
#pragma unroll
    for (int a = 0; a < 2; ++a)
#pragma unroll
        for (int q = 0; q < 4; ++q) acc[a][q] = (f32x4){0.f, 0.f, 0.f, 0.f};
    f32x4 kacc = {0.f, 0.f, 0.f, 0.f};

    // prologue: stage kb=0 into buf 0
    ld_lds16(agh, &ALDS[0][0][tid * 8]);
    ld_lds16(agl, &ALDS[0][1][tid * 8]);
    ld_lds16(Bb + tid * 8, &BLDS[0][0][tid * 8]);
    ld_lds16(Bb + 4096 + tid * 8, &BLDS[0][1][tid * 8]);
    __syncthreads();

    const int lgs = lg ^ (l15 & 3) ^ ((l15 >> 2) & 1);  // de-swizzled k-chunk
    const int arow = wm * 32 + l15;
    int buf = 0;
    for (int kb = 0; kb < 24; ++kb) {
        if (kb + 1 < 24) {
            int nb = buf ^ 1, kn = kb + 1;
            ld_lds16(agh + kn * 32, &ALDS[nb][0][tid * 8]);
            ld_lds16(agl + kn * 32, &ALDS[nb][1][tid * 8]);
            ld_lds16(Bb + (size_t)kn * 8192 + tid * 8, &BLDS[nb][0][tid * 8]);
            ld_lds16(Bb + (size_t)kn * 8192 + 4096 + tid * 8, &BLDS[nb][1][tid * 8]);
        }
        u32x4 ah[2], al2[2], bh[4], bl2[4];
#pragma unroll
        for (int mf = 0; mf < 2; ++mf) {
            int ao = (arow + mf * 16) * 32 + lgs * 8;
            ah[mf] = *(const u32x4*)&ALDS[buf][0][ao];
            al2[mf] = *(const u32x4*)&ALDS[buf][1][ao];
        }
#pragma unroll
        for (int nf = 0; nf < 4; ++nf) {
            int bo = (lg * 128 + wn * 64 + nf * 16 + l15) * 8;
            bh[nf] = *(const u32x4*)&BLDS[buf][0][bo];
            bl2[nf] = *(const u32x4*)&BLDS[buf][1][bo];
        }
#pragma unroll
        for (int mf = 0; mf < 2; ++mf)
#pragma unroll
            for (int nf = 0; nf < 4; ++nf) {
                acc[mf][nf] = mfma16(ah[mf], bh[nf], acc[mf][nf]);
                acc[mf][nf] = mfma16(al2[mf], bh[nf], acc[mf][nf]);
                acc[mf][nf] = mfma16(ah[mf], bl2[nf], acc[mf][nf]);
            }
        if (dokw && kb < 16) {   // fused kw: wave's 16x16 tile, B from L2
            size_t kwo = (size_t)kb * 8192 + (size_t)(lg * 128 + kwn) * 8;
            u32x4 kbh = *(const u32x4*)(KWb + kwo);
            u32x4 kbl = *(const u32x4*)(KWb + kwo + 4096);
            int ao2 = (wv * 16 + l15) * 32 + lgs * 8;
            u32x4 kah = *(const u32x4*)&ALDS[buf][0][ao2];
            u32x4 kal = *(const u32x4*)&ALDS[buf][1][ao2];
            kacc = mfma16(kah, kbh, kacc);
            kacc = mfma16(kal, kbh, kacc);
            kacc = mfma16(kah, kbl, kacc);
        }
        __syncthreads();
        buf ^= 1;
    }

    if (dokw) {   // write key_w(t-1) slice as fp16 (biasless; bias added in Bg)
#pragma unroll
        for (int r = 0; r < 4; ++r) {
            int row = wv * 16 + lg * 4 + r;
            Mk16[((size_t)(r0 + row) * 64 + (t - 1)) * 256 + kwcol] = (f16)kacc[r];
        }
    }

    {   // LSTM pointwise epilogue
        const int hcol = (nsel * 2 + wn) * 16 + l15;
        const int ncb = nsel * 128 + wn * 64 + l15;
        float bv[4], wv4[4];
#pragma unroll
        for (int g4 = 0; g4 < 4; ++g4) { bv[g4] = bp[ncb + g4 * 16]; wv4[g4] = wip[ncb + g4 * 16]; }
#pragma unroll
        for (int mf = 0; mf < 2; ++mf)
#pragma unroll
            for (int r = 0; r < 4; ++r) {
                const int row = wm * 32 + mf * 16 + lg * 4 + r;
                const size_t b = (size_t)(r0 + row);
                const float k2 = kr2[b];
                float iv = acc[mf][0][r] + bv[0] + k2 * wv4[0];
                float fv = acc[mf][1][r] + bv[1] + k2 * wv4[1];
                float gv = acc[mf][2][r] + bv[2] + k2 * wv4[2];
                float ov = acc[mf][3][r] + bv[3] + k2 * wv4[3];
                float cn = sigm(fv) * cst[b * 512 + hcol] + sigm(iv) * tanh_f(gv);
                cst[b * 512 + hcol] = cn;
                float h = sigm(ov) * tanh_f(cn);
                ush hh = f2bf(h);
                Whi[b * 768 + hcol] = hh;
                Wlo[b * 768 + hcol] = f2bf(h - bf2f(hh));
            }
    }
}

// ---------------------------------------------------------------------------
// Bg: finish step t attention: g-gate, late Mk[t-1] term, key_r(t+1) write.
// grid 1024 x 256; wave = one batch row.
// ---------------------------------------------------------------------------
__global__ __launch_bounds__(256)
void stepBg(int t,
            ush* __restrict__ Ahi, ush* __restrict__ Alo,
            const f16* __restrict__ Mk16,
            const float* __restrict__ readp, const float* __restrict__ wlast,
            const float* __restrict__ rcb,
            const float* __restrict__ Wg, const float* __restrict__ bg,
            const float* __restrict__ bkw, float* __restrict__ kr2)
{
    const int tid = threadIdx.x, l = tid & 63, wv = tid >> 6;
    const size_t b = (size_t)blockIdx.x * 4 + wv;
    // g = sigmoid(h . Wg + bg); lane owns 8 h-cols
    u32x4 hv = *(const u32x4*)(Ahi + b * 768 + l * 8);
    u32x4 lv = *(const u32x4*)(Alo + b * 768 + l * 8);
    float gd = 0.f;
#pragma unroll
    for (int j = 0; j < 4; ++j) {
        float h0 = bf2f((ush)(hv[j] & 0xffffu)) + bf2f((ush)(lv[j] & 0xffffu));
        float h1 = bf2f((ush)(hv[j] >> 16)) + bf2f((ush)(lv[j] >> 16));
        gd += h0 * Wg[l * 8 + j * 2] + h1 * Wg[l * 8 + j * 2 + 1];
    }
#pragma unroll
    for (int o = 1; o < 64; o <<= 1) gd += __shfl_xor(gd, o);
    const float g = sigm(gd + bg[0]);
    // key_r = g * (partial + w_{t-1}*Mk[t-1] + bkw)
    const float wl = wlast[b];
    f32x4 rp = *(const f32x4*)(readp + b * 256 + l * 4);
    f16x4 mk = *(const f16x4*)(Mk16 + b * 16384 + (size_t)(t - 1) * 256 + l * 4);
    f32x4 bk = *(const f32x4*)(bkw + l * 4);
    ush oh[4], ol[4];
#pragma unroll
    for (int j = 0; j < 4; ++j) {
        float v = g * (rp[j] + wl * (float)mk[j] + bk[j]);
        oh[j] = f2bf(v);
        ol[j] = f2bf(v - bf2f(oh[j]));
    }
    *(ushort4*)(Ahi + b * 768 + 512 + l * 4) = *(ushort4*)oh;
    *(ushort4*)(Alo + b * 768 + 512 + l * 4) = *(ushort4*)ol;
    if (l == 0) kr2[b] = g * rcb[b];
}

// ---------------------------------------------------------------------------
// stepY: out = h(64) @ W_y + b_y   (fp32)
// ---------------------------------------------------------------------------
__global__ __launch_bounds__(256)
void stepY(const ush* __restrict__ Ahi, const ush* __restrict__ Alo,
           const float* __restrict__ Wy, const float* __restrict__ by,
           float* __restrict__ out)
{
    __shared__ float hL[4][512];
    const int tid = threadIdx.x;
    const size_t b0 = (size_t)blockIdx.x * 4;
    for (int i = tid; i < 2048; i += 256) {
        int rr = i >> 9, k = i & 511;
        hL[rr][k] = bf2f(Ahi[(b0 + rr) * 768 + k]) + bf2f(Alo[(b0 + rr) * 768 + k]);
    }
    __syncthreads();
    const int col = tid & 127, rA = tid >> 7;
    float a0 = by[col], a1 = a0;
    for (int k = 0; k < 512; ++k) {
        float wyv = Wy[k * 128 + col];
        a0 += hL[rA][k] * wyv;
        a1 += hL[rA + 2][k] * wyv;
    }
    out[(b0 + rA) * 128 + col] = a0;
    out[(b0 + rA + 2) * 128 + col] = a1;
}

// ---------------------------------------------------------------------------
extern "C" void kernel_launch(void* const* d_in, const int* in_sizes, int n_in,
                              void* d_out, int out_size, void* d_ws, size_t ws_size,
                              hipStream_t stream) {
    const float* z   = (const float*)d_in[0];
    const float* Wi  = (const float*)d_in[1];
    const float* Wh  = (const float*)d_in[2];
    const float* bl  = (const float*)d_in[3];
    const float* Wkw = (const float*)d_in[4];
    const float* bkw = (const float*)d_in[5];
    const float* Wg  = (const float*)d_in[6];
    const float* bg  = (const float*)d_in[7];
    const float* Wy  = (const float*)d_in[8];
    const float* by  = (const float*)d_in[9];
    const float* cg  = (const float*)d_in[10];
    const float* cb  = (const float*)d_in[11];

    char* wsb = (char*)d_ws;
    ush*   WBsw  = (ush*)(wsb + 0);             //   6,291,456
    ush*   KWsw  = (ush*)(wsb + 6291456);       //     524,288
    float* bp    = (float*)(wsb + 6815744);     //       8,192
    float* wip   = (float*)(wsb + 6823936);     //       8,192
    float* kr2   = (float*)(wsb + 6832128);     //      16,384
    float* cst   = (float*)(wsb + 6848512);     //   8,388,608
    ush*   Abuf  = (ush*)(wsb + 15237120);      //  25,165,824
    float* Gpk   = (float*)(wsb + 40402944);    //  33,030,144
    f16*   Mk16  = (f16*)(wsb + 73433088);      // 134,217,728  [b][t][k] fp16
    float* readp = (float*)(wsb + 207650816);   //   4,194,304
    float* wlast = (float*)(wsb + 211845120);   //      16,384
    float* rcb   = (float*)(wsb + 211861504);   //      16,384
    float* out   = (float*)d_out;

    hipMemsetAsync(Abuf, 0, 25165824, stream);
    hipMemsetAsync(cst, 0, 8388608, stream);
    hipMemsetAsync(kr2, 0, 16384, stream);

    prep_w<<<840, 256, 0, stream>>>(Wi, Wh, Wkw, bl, WBsw, KWsw, bp, wip);
    gram_k<<<4096, 256, 0, stream>>>(z, Gpk);

    auto Ap = [&](int par, int pl) { return Abuf + ((size_t)par * 2 + pl) * 3145728; };

    for (int t = 0; t <= 64; ++t) {
        int pr = t & 1;
        stepA<<<2560, 512, 0, stream>>>(t, Ap(pr, 0), Ap(pr, 1), Ap(pr ^ 1, 0), Ap(pr ^ 1, 1),
                                        WBsw, KWsw, bp, wip, kr2, cst, Mk16,
                                        Gpk, readp, wlast, rcb, cg, cb);
        if (t >= 1 && t < 64)
            stepBg<<<1024, 256, 0, stream>>>(t, Ap(pr ^ 1, 0), Ap(pr ^ 1, 1), Mk16,
                                             readp, wlast, rcb, Wg, bg, bkw, kr2);
    }
    stepY<<<1024, 256, 0, stream>>>(Ap(1, 0), Ap(1, 1), Wy, by, out);
}